// Round 1
// baseline (206.666 us; speedup 1.0000x reference)
//
#include <hip/hip_runtime.h>
#include <math.h>

#define BATCH 64
#define LSEQ 2048
#define DMOD 256
#define KC 32
#define LCHUNK 128  // l's per block (halved: 1024 blocks -> fills 4 blocks/CU)
#define NCHUNK 16   // LSEQ / LCHUNK
#define LS 32       // l's per subtile
#define NSUB 4      // LCHUNK / LS
#define PITCH_D 260 // bf16 pitch for d-fast tiles (stride 520B -> 2-bank row skew, conflict-free col reads)
#define PITCH_L 40  // bf16 pitch for l-fast tiles (stride 80B -> 2-way banks, free)

typedef __bf16 bf16x8 __attribute__((ext_vector_type(8)));
typedef __bf16 bf16x4 __attribute__((ext_vector_type(4)));
typedef float f32x4 __attribute__((ext_vector_type(4)));

// One block: (b, 128-l chunk). Computes C_u[32][256] = sum_l exp(s[l,k])*rev[l,d]
// and Z[32] = sum_l exp(s[l,k]) over its chunk (no max subtraction: |s| <~ 7).
// LDS diet vs prev version: W lives in 32 VGPRs of A-fragments (no sW) ->
// 39.9 KB LDS/block -> 4 blocks/CU (was 57 KB -> 2 blocks/CU).
__global__ __launch_bounds__(256, 4) void fused_pool_kernel(
    const float* __restrict__ rev, const float* __restrict__ W,
    float* __restrict__ cPartial, float* __restrict__ zPartial) {
  __shared__ __align__(16) __bf16 sRev[LS * PITCH_D];    // rev[l][d], d-fast (GEMM1 B)
  __shared__ __align__(16) __bf16 sRevT[DMOD * PITCH_L]; // rev[d][l], l-fast (GEMM2 B)
  __shared__ __align__(16) __bf16 sP[KC * PITCH_L];      // p[k][l], l-fast (GEMM2 A)
  __shared__ float sZw[2][KC];

  const int tid = threadIdx.x;
  const int b = blockIdx.y;
  const int lc = blockIdx.x;
  const int lbase = lc * LCHUNK;
  const int wave = tid >> 6;
  const int lane = tid & 63;
  const int col = lane & 15;
  const int quad = lane >> 4;

  const int Mt = wave & 1;   // k-half (both GEMMs)
  const int Nt = wave >> 1;  // GEMM1: l-half of subtile; GEMM2: d-half group

  // W A-fragments in registers (reused by every subtile; saves 16.9 KB LDS and
  // 8 b128 LDS reads per subtile). wfrag[ks][j] = W[Mt*16+col][ks*32+quad*8+j].
  bf16x8 wfrag[8];
  {
    const float* wp = W + (Mt * 16 + col) * DMOD + quad * 8;
#pragma unroll
    for (int ks = 0; ks < 8; ++ks) {
      float4 va = *(const float4*)(wp + ks * 32);
      float4 vb = *(const float4*)(wp + ks * 32 + 4);
      wfrag[ks] = (bf16x8){(__bf16)va.x, (__bf16)va.y, (__bf16)va.z, (__bf16)va.w,
                           (__bf16)vb.x, (__bf16)vb.y, (__bf16)vb.z, (__bf16)vb.w};
    }
  }

  f32x4 acc2[8];
#pragma unroll
  for (int i = 0; i < 8; ++i) acc2[i] = (f32x4){0.f, 0.f, 0.f, 0.f};
  float zacc[4] = {0.f, 0.f, 0.f, 0.f};

  for (int sub = 0; sub < NSUB; ++sub) {
    const int l0 = lbase + sub * LS;
    __syncthreads();  // prev GEMM2 done before overwriting sRev/sRevT/sP
    // stage rev subtile 32x256 fp32 -> bf16 sRev (coalesced: one row per wave-load)
#pragma unroll
    for (int i = 0; i < 8; ++i) {
      int slot = tid + 256 * i;  // 2048 float4 slots
      int r = slot >> 6, c4 = slot & 63;
      float4 v = *(const float4*)(rev + ((size_t)b * LSEQ + l0 + r) * DMOD + c4 * 4);
      bf16x4 h = {(__bf16)v.x, (__bf16)v.y, (__bf16)v.z, (__bf16)v.w};
      *(bf16x4*)(&sRev[r * PITCH_D + c4 * 4]) = h;
    }
    __syncthreads();  // sRev visible

    // transpose pass: sRev[l][d] -> sRevT[d][l]. u16 column reads (conflict-free:
    // consecutive lanes read consecutive d, pair-sharing dwords) + b128 row writes.
#pragma unroll
    for (int j4 = 0; j4 < 4; ++j4) {
      bf16x8 v;
#pragma unroll
      for (int j = 0; j < 8; ++j) v[j] = sRev[(j4 * 8 + j) * PITCH_D + tid];
      *(bf16x8*)(&sRevT[tid * PITCH_L + j4 * 8]) = v;
    }

    // GEMM1: s^T tile [16 k (Mt)][16 l (Nt)], K=256 over 8 steps.
    // A = wfrag (regs); B = rev (B[kd=d][n=l]).
    f32x4 acc1 = {0.f, 0.f, 0.f, 0.f};
#pragma unroll
    for (int ks = 0; ks < 8; ++ks) {
      bf16x8 bfrag = *(const bf16x8*)(&sRev[(Nt * 16 + col) * PITCH_D + ks * 32 + quad * 8]);
      acc1 = __builtin_amdgcn_mfma_f32_16x16x32_bf16(wfrag[ks], bfrag, acc1, 0, 0, 0);
    }
    // C/D layout: row(m=k) = quad*4+reg, col(n=l) = lane&15.
#pragma unroll
    for (int reg = 0; reg < 4; ++reg) {
      float p = __expf(acc1[reg]);
      __bf16 ph = (__bf16)p;
      zacc[reg] += (float)ph;  // z consistent with bf16-rounded numerator
      sP[(Mt * 16 + quad * 4 + reg) * PITCH_L + Nt * 16 + col] = ph;
    }
    __syncthreads();  // sP + sRevT visible

    // GEMM2: C[16 k (Mt)][128 d (Nt-group)], K=32 (one step).
    // A = P^T from sP[k][l-fast]; B = rev from sRevT[d][l-fast].
    bf16x8 pa = *(const bf16x8*)(&sP[(Mt * 16 + col) * PITCH_L + quad * 8]);
#pragma unroll
    for (int nt = 0; nt < 8; ++nt) {
      int dt = Nt * 8 + nt;
      bf16x8 bb = *(const bf16x8*)(&sRevT[(dt * 16 + col) * PITCH_L + quad * 8]);
      acc2[nt] = __builtin_amdgcn_mfma_f32_16x16x32_bf16(pa, bb, acc2[nt], 0, 0, 0);
    }
  }

  // Z: reduce over the 16 col-lanes (l), stash per (Nt) row, combine.
#pragma unroll
  for (int off = 1; off < 16; off <<= 1)
#pragma unroll
    for (int reg = 0; reg < 4; ++reg) zacc[reg] += __shfl_xor(zacc[reg], off, 64);
  if (col == 0) {
#pragma unroll
    for (int reg = 0; reg < 4; ++reg)
      sZw[Nt][Mt * 16 + quad * 4 + reg] = zacc[reg];
  }
  __syncthreads();
  if (tid < KC)
    zPartial[((size_t)b * NCHUNK + lc) * KC + tid] = sZw[0][tid] + sZw[1][tid];

  // C partial store: row(m=k)=quad*4+reg, col(n=d)=lane&15.
  float* dst = cPartial + (((size_t)b * NCHUNK + lc) * KC) * DMOD;
#pragma unroll
  for (int nt = 0; nt < 8; ++nt) {
    int d = (Nt * 8 + nt) * 16 + col;
#pragma unroll
    for (int reg = 0; reg < 4; ++reg) {
      int k = Mt * 16 + quad * 4 + reg;
      dst[k * DMOD + d] = acc2[nt][reg];
    }
  }
}

// out[b][k][d] = sum_lc C_u / sum_lc Z
__global__ __launch_bounds__(256) void reduce_kernel(
    const float* __restrict__ cPartial, const float* __restrict__ zPartial,
    float* __restrict__ out) {
  int idx = blockIdx.x * 256 + threadIdx.x;  // 524288
  int b = idx >> 13;
  int k = (idx >> 8) & 31;
  int d = idx & 255;
  float s = 0.f, z = 0.f;
#pragma unroll
  for (int lcc = 0; lcc < NCHUNK; ++lcc) {
    s += cPartial[(((size_t)b * NCHUNK + lcc) * KC + k) * DMOD + d];
    z += zPartial[((size_t)b * NCHUNK + lcc) * KC + k];
  }
  out[idx] = s / z;
}

extern "C" void kernel_launch(void* const* d_in, const int* in_sizes, int n_in,
                              void* d_out, int out_size, void* d_ws,
                              size_t ws_size, hipStream_t stream) {
  const float* rev = (const float*)d_in[0];  // 64*2048*256 fp32
  const float* W = (const float*)d_in[1];    // 32*256 fp32
  float* out = (float*)d_out;                // 64*32*256 fp32

  float* ws = (float*)d_ws;
  float* cPartial = ws;  // 64*16*32*256 floats (33.6 MB)
  float* zPartial = cPartial + (size_t)BATCH * NCHUNK * KC * DMOD;  // 64*16*32 floats

  fused_pool_kernel<<<dim3(NCHUNK, BATCH), dim3(256), 0, stream>>>(rev, W, cPartial,
                                                                   zPartial);
  reduce_kernel<<<dim3(2048), dim3(256), 0, stream>>>(cPartial, zPartial, out);
}

// Round 2
// 197.544 us; speedup vs baseline: 1.0462x; 1.0462x over previous
//
#include <hip/hip_runtime.h>
#include <math.h>

#define BATCH 64
#define LSEQ 2048
#define DMOD 256
#define KC 32
#define LCHUNK 256  // l's per block
#define NCHUNK 8    // LSEQ / LCHUNK (reverted: halves cPartial traffic vs 16)
#define LS 32       // l's per subtile
#define NSUB 8      // LCHUNK / LS
#define PITCH_D 260 // bf16 pitch for d-fast tiles (stride 520B, conflict-free col reads)
#define PITCH_L 40  // bf16 pitch for l-fast tiles (stride 80B -> 2-way banks, free)

typedef __bf16 bf16x8 __attribute__((ext_vector_type(8)));
typedef __bf16 bf16x4 __attribute__((ext_vector_type(4)));
typedef float f32x4 __attribute__((ext_vector_type(4)));

// One block: (b, 256-l chunk). Computes C_u[32][256] = sum_l exp(s[l,k])*rev[l,d]
// and Z[32] = sum_l exp(s[l,k]) over its chunk (no max subtraction: |s| <~ 7).
// Pipeline (T14): subtile i+1's global loads are issued into registers right
// after subtile i's LDS store, staying in flight across both barriers and all
// compute of subtile i. 2 barriers/subtile (was 3): writing sRev only needs all
// waves past prev GEMM1, which the prev sP-barrier already guarantees (GEMM2
// never reads sRev).
__global__ __launch_bounds__(256, 2) void fused_pool_kernel(
    const float* __restrict__ rev, const float* __restrict__ W,
    float* __restrict__ cPartial, float* __restrict__ zPartial) {
  __shared__ __align__(16) __bf16 sRev[LS * PITCH_D];    // rev[l][d], d-fast (GEMM1 B)
  __shared__ __align__(16) __bf16 sRevT[DMOD * PITCH_L]; // rev[d][l], l-fast (GEMM2 B)
  __shared__ __align__(16) __bf16 sP[KC * PITCH_L];      // p[k][l], l-fast (GEMM2 A)
  __shared__ float sZw[2][KC];

  const int tid = threadIdx.x;
  const int b = blockIdx.y;
  const int lc = blockIdx.x;
  const int lbase = lc * LCHUNK;
  const int wave = tid >> 6;
  const int lane = tid & 63;
  const int col = lane & 15;
  const int quad = lane >> 4;

  const int Mt = wave & 1;   // k-half (both GEMMs)
  const int Nt = wave >> 1;  // GEMM1: l-half of subtile; GEMM2: d-half group

  // W A-fragments in registers (reused by every subtile; saves 16.9 KB LDS and
  // 8 b128 LDS reads per subtile). wfrag[ks][j] = W[Mt*16+col][ks*32+quad*8+j].
  bf16x8 wfrag[8];
  {
    const float* wp = W + (Mt * 16 + col) * DMOD + quad * 8;
#pragma unroll
    for (int ks = 0; ks < 8; ++ks) {
      float4 va = *(const float4*)(wp + ks * 32);
      float4 vb = *(const float4*)(wp + ks * 32 + 4);
      wfrag[ks] = (bf16x8){(__bf16)va.x, (__bf16)va.y, (__bf16)va.z, (__bf16)va.w,
                           (__bf16)vb.x, (__bf16)vb.y, (__bf16)vb.z, (__bf16)vb.w};
    }
  }

  f32x4 acc2[8];
#pragma unroll
  for (int i = 0; i < 8; ++i) acc2[i] = (f32x4){0.f, 0.f, 0.f, 0.f};
  float zacc[4] = {0.f, 0.f, 0.f, 0.f};

  // Per-wave staging geometry: wave w holds rows (4*i + w) of the 32-row
  // subtile, lanes span d = lane*4 .. lane*4+3 (fully coalesced float4).
  const float* rowp = rev + ((size_t)b * LSEQ + lbase) * DMOD + lane * 4;

  float4 r[8];
  // prologue: load subtile 0
#pragma unroll
  for (int i = 0; i < 8; ++i)
    r[i] = *(const float4*)(rowp + (size_t)(4 * i + wave) * DMOD);

  for (int sub = 0; sub < NSUB; ++sub) {
    // r -> bf16 sRev. Safe without a leading barrier: all waves are past the
    // prev sP-barrier, hence past their GEMM1/transpose reads of sRev.
#pragma unroll
    for (int i = 0; i < 8; ++i) {
      float4 v = r[i];
      bf16x4 h = {(__bf16)v.x, (__bf16)v.y, (__bf16)v.z, (__bf16)v.w};
      *(bf16x4*)(&sRev[(4 * i + wave) * PITCH_D + lane * 4]) = h;
    }
    // prefetch subtile sub+1 into r (in flight across both barriers + compute)
    if (sub + 1 < NSUB) {
      const float* np = rowp + (size_t)((sub + 1) * LS) * DMOD;
#pragma unroll
      for (int i = 0; i < 8; ++i)
        r[i] = *(const float4*)(np + (size_t)(4 * i + wave) * DMOD);
    }
    __syncthreads();  // barrier A: sRev visible; all waves past prev GEMM2
                      // (so sRevT/sP below are safe to overwrite)

    // transpose pass: sRev[l][d] -> sRevT[d][l]. u16 column reads (conflict-free:
    // consecutive lanes read consecutive d, pair-sharing dwords) + b128 row writes.
#pragma unroll
    for (int j4 = 0; j4 < 4; ++j4) {
      bf16x8 v;
#pragma unroll
      for (int j = 0; j < 8; ++j) v[j] = sRev[(j4 * 8 + j) * PITCH_D + tid];
      *(bf16x8*)(&sRevT[tid * PITCH_L + j4 * 8]) = v;
    }

    // GEMM1: s^T tile [16 k (Mt)][16 l (Nt)], K=256 over 8 steps.
    // A = wfrag (regs); B = rev (B[kd=d][n=l]).
    f32x4 acc1 = {0.f, 0.f, 0.f, 0.f};
#pragma unroll
    for (int ks = 0; ks < 8; ++ks) {
      bf16x8 bfrag = *(const bf16x8*)(&sRev[(Nt * 16 + col) * PITCH_D + ks * 32 + quad * 8]);
      acc1 = __builtin_amdgcn_mfma_f32_16x16x32_bf16(wfrag[ks], bfrag, acc1, 0, 0, 0);
    }
    // C/D layout: row(m=k) = quad*4+reg, col(n=l) = lane&15.
#pragma unroll
    for (int reg = 0; reg < 4; ++reg) {
      float p = __expf(acc1[reg]);
      __bf16 ph = (__bf16)p;
      zacc[reg] += (float)ph;  // z consistent with bf16-rounded numerator
      sP[(Mt * 16 + quad * 4 + reg) * PITCH_L + Nt * 16 + col] = ph;
    }
    __syncthreads();  // barrier B: sP + sRevT visible

    // GEMM2: C[16 k (Mt)][128 d (Nt-group)], K=32 (one step).
    // A = P^T from sP[k][l-fast]; B = rev from sRevT[d][l-fast].
    bf16x8 pa = *(const bf16x8*)(&sP[(Mt * 16 + col) * PITCH_L + quad * 8]);
#pragma unroll
    for (int nt = 0; nt < 8; ++nt) {
      int dt = Nt * 8 + nt;
      bf16x8 bb = *(const bf16x8*)(&sRevT[(dt * 16 + col) * PITCH_L + quad * 8]);
      acc2[nt] = __builtin_amdgcn_mfma_f32_16x16x32_bf16(pa, bb, acc2[nt], 0, 0, 0);
    }
  }

  // Z: reduce over the 16 col-lanes (l), stash per (Nt) row, combine.
#pragma unroll
  for (int off = 1; off < 16; off <<= 1)
#pragma unroll
    for (int reg = 0; reg < 4; ++reg) zacc[reg] += __shfl_xor(zacc[reg], off, 64);
  if (col == 0) {
#pragma unroll
    for (int reg = 0; reg < 4; ++reg)
      sZw[Nt][Mt * 16 + quad * 4 + reg] = zacc[reg];
  }
  __syncthreads();
  if (tid < KC)
    zPartial[((size_t)b * NCHUNK + lc) * KC + tid] = sZw[0][tid] + sZw[1][tid];

  // C partial store: row(m=k)=quad*4+reg, col(n=d)=lane&15.
  float* dst = cPartial + (((size_t)b * NCHUNK + lc) * KC) * DMOD;
#pragma unroll
  for (int nt = 0; nt < 8; ++nt) {
    int d = (Nt * 8 + nt) * 16 + col;
#pragma unroll
    for (int reg = 0; reg < 4; ++reg) {
      int k = Mt * 16 + quad * 4 + reg;
      dst[k * DMOD + d] = acc2[nt][reg];
    }
  }
}

// out[b][k][d] = sum_lc C_u / sum_lc Z
__global__ __launch_bounds__(256) void reduce_kernel(
    const float* __restrict__ cPartial, const float* __restrict__ zPartial,
    float* __restrict__ out) {
  int idx = blockIdx.x * 256 + threadIdx.x;  // 524288
  int b = idx >> 13;
  int k = (idx >> 8) & 31;
  int d = idx & 255;
  float s = 0.f, z = 0.f;
#pragma unroll
  for (int lcc = 0; lcc < NCHUNK; ++lcc) {
    s += cPartial[(((size_t)b * NCHUNK + lcc) * KC + k) * DMOD + d];
    z += zPartial[((size_t)b * NCHUNK + lcc) * KC + k];
  }
  out[idx] = s / z;
}

extern "C" void kernel_launch(void* const* d_in, const int* in_sizes, int n_in,
                              void* d_out, int out_size, void* d_ws,
                              size_t ws_size, hipStream_t stream) {
  const float* rev = (const float*)d_in[0];  // 64*2048*256 fp32
  const float* W = (const float*)d_in[1];    // 32*256 fp32
  float* out = (float*)d_out;                // 64*32*256 fp32

  float* ws = (float*)d_ws;
  float* cPartial = ws;  // 64*8*32*256 floats (16.8 MB)
  float* zPartial = cPartial + (size_t)BATCH * NCHUNK * KC * DMOD;  // 64*8*32 floats

  fused_pool_kernel<<<dim3(NCHUNK, BATCH), dim3(256), 0, stream>>>(rev, W, cPartial,
                                                                   zPartial);
  reduce_kernel<<<dim3(2048), dim3(256), 0, stream>>>(cPartial, zPartial, out);
}